// Round 9
// baseline (156.770 us; speedup 1.0000x reference)
//
#include <hip/hip_runtime.h>

#define Bn 2
#define Cn 64
#define Hn 224
#define Wn 224
#define HWn (Hn*Wn)
#define WSn 32
#define OVn 8
#define STRIDEn 24
#define NHn 9
#define NWn 9
#define NWT 28                 // W/8 tiles per row
#define VROW (NWT*Cn*8)        // 14336 elements per (b,h) row in vb2
#define QSCALE (1.44269504088896f/32.0f)

typedef __bf16 bf16x8 __attribute__((ext_vector_type(8)));
typedef float f32x16 __attribute__((ext_vector_type(16)));
typedef unsigned int uint4v __attribute__((ext_vector_type(4)));

union PackU { uint4v u; bf16x8 h; };
union BfPair { __bf16 h[2]; unsigned u; };

__device__ __forceinline__ float fast_exp2(float x) {
#if __has_builtin(__builtin_amdgcn_exp2f)
  return __builtin_amdgcn_exp2f(x);
#else
  return exp2f(x);
#endif
}

__device__ __forceinline__ float fast_rcp(float x) {
#if __has_builtin(__builtin_amdgcn_rcpf)
  return __builtin_amdgcn_rcpf(x);
#else
  return 1.0f / x;
#endif
}

__device__ __forceinline__ float bflo(unsigned u) { return __uint_as_float(u << 16); }
__device__ __forceinline__ float bfhi(unsigned u) { return __uint_as_float(u & 0xffff0000u); }

// fade weight factor for window index i, in-window position p
__device__ __forceinline__ float edge_w(int i, int p) {
  float w = 1.0f;
  if (i > 0 && p < OVn)            w *= (float)p * (1.0f/7.0f);
  if (i < NHn-1 && p >= WSn-OVn)   w *= (float)(WSn-1-p) * (1.0f/7.0f);
  return w;
}

// separable coverage sum
__device__ __forceinline__ float covsum(int h) {
  int ihi = h / STRIDEn; if (ihi > NHn-1) ihi = NHn-1;
  float s = edge_w(ihi, h - STRIDEn*ihi);
  int ilo = ihi - 1;
  if (ilo >= 0) {
    int p = h - STRIDEn*ilo;
    if (p < WSn) s += edge_w(ilo, p);
  }
  return s;
}

// ---------------- QKV projection: fp32 in, bf16 out ----------------
// 3-role split (4704 waves): role 0: q8+k8; roles 1,2: v halves.
// (5-role split measured WORSE: extra x re-reads cost ~3.6us. Keep 3.)
// qb: [pix][8] bf16 PRE-SCALED by log2e/32.  kb: [pix][8] bf16.
// vb2: [b][h][w/8][c][w%8] bf16 (w8-tiled, coalesced PV fragment loads).
__global__ __launch_bounds__(256) void qkv_kernel(
    const float* __restrict__ x,
    const float* __restrict__ Wq, const float* __restrict__ bq,
    const float* __restrict__ Wk, const float* __restrict__ bk,
    const float* __restrict__ Wv, const float* __restrict__ bv,
    __bf16* __restrict__ qb, __bf16* __restrict__ kb, __bf16* __restrict__ vb2)
{
  __shared__ float sW[32*64];
  __shared__ float sb2[32];
  int bid = blockIdx.x;
  int pb = bid / 3, role = bid - pb*3;
  int tid = threadIdx.x;

  if (role == 0) {
    for (int i = tid; i < 8*64; i += 256) { sW[i] = Wq[i]; sW[512 + i] = Wk[i]; }
    if (tid < 8) { sb2[tid] = bq[tid]; sb2[8 + tid] = bk[tid]; }
  } else {
    const float* Wsrc = Wv + (size_t)(role-1)*32*64;
    for (int i = tid; i < 32*64; i += 256) sW[i] = Wsrc[i];
    if (tid < 32) sb2[tid] = bv[(role-1)*32 + tid];
  }
  __syncthreads();

  int pix = pb*256 + tid;                // B*H*W = 100352 = 392*256
  int b  = pix / HWn;
  int hw = pix - b * HWn;
  const float* xp = x + (size_t)b * Cn * HWn + hw;
  float xr[64];
  #pragma unroll
  for (int c = 0; c < 64; ++c) xr[c] = xp[(size_t)c * HWn];

  if (role == 0) {
    float q8[8], k8[8];
    #pragma unroll
    for (int o = 0; o < 8; ++o) {
      const float4* wrq = (const float4*)(sW + o*64);
      const float4* wrk = (const float4*)(sW + 512 + o*64);
      float sq = sb2[o], sk = sb2[8+o];
      #pragma unroll
      for (int c4 = 0; c4 < 16; ++c4) {
        float4 wq4 = wrq[c4]; float4 wk4 = wrk[c4];
        sq = fmaf(wq4.x, xr[4*c4+0], sq); sq = fmaf(wq4.y, xr[4*c4+1], sq);
        sq = fmaf(wq4.z, xr[4*c4+2], sq); sq = fmaf(wq4.w, xr[4*c4+3], sq);
        sk = fmaf(wk4.x, xr[4*c4+0], sk); sk = fmaf(wk4.y, xr[4*c4+1], sk);
        sk = fmaf(wk4.z, xr[4*c4+2], sk); sk = fmaf(wk4.w, xr[4*c4+3], sk);
      }
      q8[o] = sq; k8[o] = sk;
    }
    PackU qo, ko;
    #pragma unroll
    for (int o = 0; o < 8; ++o) {
      qo.h[o] = (__bf16)(q8[o] * QSCALE);
      ko.h[o] = (__bf16)k8[o];
    }
    *(uint4v*)(qb + (size_t)pix*8) = qo.u;
    *(uint4v*)(kb + (size_t)pix*8) = ko.u;
  } else {
    int h = hw / Wn, w = hw - h*Wn;
    __bf16* vo = vb2 + (((size_t)(b*Hn + h)*NWT + (w >> 3))*Cn + (size_t)(role-1)*32)*8 + (w & 7);
    for (int og = 0; og < 8; ++og) {
      #pragma unroll
      for (int t = 0; t < 4; ++t) {
        int o = og*4 + t;
        const float4* wr = (const float4*)(sW + o*64);
        float s = sb2[o];
        #pragma unroll
        for (int c4 = 0; c4 < 16; ++c4) {
          float4 w4 = wr[c4];
          s = fmaf(w4.x, xr[4*c4+0], s); s = fmaf(w4.y, xr[4*c4+1], s);
          s = fmaf(w4.z, xr[4*c4+2], s); s = fmaf(w4.w, xr[4*c4+3], s);
        }
        vo[(size_t)o * 8] = (__bf16)s;
      }
    }
  }
}

// ---------------- MFMA flash attention ----------------
// One wave = (window, query-row ph): all 1024 keys, fully independent.
// Block = 256 threads = 4 waves (4 ph rows); grid = 162*8 = 1296 blocks.
// ZERO LDS, ZERO barriers, no merge: raw O stored in MFMA-fragment order
// (bf16x2 rows, coalesced) + per-query lsum row (fp32); final_kernel decodes.
// obu row layout: [win][ph][nh(2)][t(8)] x 64 lanes; row value = pack(acc[2t],acc[2t+1]).
__global__ __launch_bounds__(256, 4) void attn_kernel(
    const __bf16* __restrict__ qb, const __bf16* __restrict__ kb,
    const __bf16* __restrict__ vb2, unsigned* __restrict__ obu,
    float* __restrict__ lsumb)
{
  // XCD swizzle: 1296 = 8*162; all 8 blocks of a window land on one XCD.
  int bid = blockIdx.x;
  int bidm = (bid & 7) * 162 + (bid >> 3);
  int win = bidm >> 3;            // 0..161
  int rg  = bidm & 7;             // row-group 0..7
  int b  = win / (NHn*NWn);
  int ij = win - b*(NHn*NWn);
  int wi = ij / NWn;
  int wj = ij - wi*NWn;

  int tid  = threadIdx.x;
  int widx = tid >> 6;            // wave 0..3
  int lane = tid & 63;
  int ph = rg*4 + widx;           // query row 0..31
  int lo = lane & 31, hi = lane >> 5;
  int h0 = wi*STRIDEn, w0 = wj*STRIDEn;

  // Q fragment (B operand): lane holds Q[query=lo][ch=8*hi+j]; hi lanes zeroed (ch 8..15 pad)
  bf16x8 qf = *(const bf16x8*)(qb + ((size_t)(b*Hn + h0 + ph)*Wn + w0 + lo) * 8);
  if (hi) qf = (bf16x8){};

  // K rows; hi lanes duplicate lo (annihilated by qf==0 rows)
  const __bf16* kbase = kb + ((size_t)(b*Hn + h0)*Wn + w0 + lo) * 8;
  // V in w8-tiled layout; lane (lo,hi) -> (ch=lo, wtile=w0/8 + hi)
  const __bf16* vbase = vb2 + (((size_t)(b*Hn + h0)*NWT + (w0>>3))*Cn + lo)*8
                        + (size_t)hi*512;

  f32x16 acc0 = {}, acc1 = {};
  float ls[4] = {0.f, 0.f, 0.f, 0.f};   // partial sums break the serial add chain

  #pragma unroll 4
  for (int kt = 0; kt < 32; ++kt) {
    bf16x8 kf = *(const bf16x8*)(kbase + (size_t)kt*Wn*8);

    const __bf16* vk = vbase + (size_t)kt*VROW;
    bf16x8 vf00 = *(const bf16x8*)(vk);           // keys 8*hi+j,    ch lo
    bf16x8 vf01 = *(const bf16x8*)(vk + 256);     // keys 8*hi+j,    ch lo+32
    bf16x8 vf10 = *(const bf16x8*)(vk + 1024);    // keys 16+8*hi+j, ch lo
    bf16x8 vf11 = *(const bf16x8*)(vk + 1280);    // keys 16+8*hi+j, ch lo+32

    // S[key][query]: key=(r&3)+8*(r>>2)+4*hi (w-offset), query=lo. log2 domain.
    f32x16 s = __builtin_amdgcn_mfma_f32_32x32x16_bf16(kf, qf, (f32x16){}, 0, 0, 0);

    unsigned w[8];
    #pragma unroll
    for (int d = 0; d < 8; ++d) {
      float a  = fast_exp2(s[2*d]);
      float b2 = fast_exp2(s[2*d+1]);
      ls[d & 3] += a + b2;
      BfPair pr; pr.h[0] = (__bf16)a; pr.h[1] = (__bf16)b2;
      w[d] = pr.u;
    }
    // permlane32_swap: one op yields BOTH PV-fragment words.
    auto s02 = __builtin_amdgcn_permlane32_swap((int)w[0], (int)w[2], false, false);
    auto s13 = __builtin_amdgcn_permlane32_swap((int)w[1], (int)w[3], false, false);
    auto s46 = __builtin_amdgcn_permlane32_swap((int)w[4], (int)w[6], false, false);
    auto s57 = __builtin_amdgcn_permlane32_swap((int)w[5], (int)w[7], false, false);

    PackU pa0, pa1;
    pa0.u = (uint4v){(unsigned)s02[0], (unsigned)s13[0], (unsigned)s02[1], (unsigned)s13[1]};
    pa1.u = (uint4v){(unsigned)s46[0], (unsigned)s57[0], (unsigned)s46[1], (unsigned)s57[1]};

    __builtin_amdgcn_s_setprio(1);
    acc0 = __builtin_amdgcn_mfma_f32_32x32x16_bf16(pa0.h, vf00, acc0, 0, 0, 0);
    acc1 = __builtin_amdgcn_mfma_f32_32x32x16_bf16(pa0.h, vf01, acc1, 0, 0, 0);
    acc0 = __builtin_amdgcn_mfma_f32_32x32x16_bf16(pa1.h, vf10, acc0, 0, 0, 0);
    acc1 = __builtin_amdgcn_mfma_f32_32x32x16_bf16(pa1.h, vf11, acc1, 0, 0, 0);
    __builtin_amdgcn_s_setprio(0);
  }

  float lsum = (ls[0] + ls[1]) + (ls[2] + ls[3]);
  // partner half-wave holds the complementary key set for the same query lo
  lsum += __shfl_xor(lsum, 32);

  // fragment-order stores: 16 coalesced bf16x2 rows + 1 fp32 lsum row.
  size_t rowbase = ((size_t)win*32 + ph) * 16;
  #pragma unroll
  for (int t = 0; t < 8; ++t) {
    BfPair p0; p0.h[0] = (__bf16)acc0[2*t]; p0.h[1] = (__bf16)acc0[2*t+1];
    obu[(rowbase + t)*64 + lane] = p0.u;
  }
  #pragma unroll
  for (int t = 0; t < 8; ++t) {
    BfPair p1; p1.h[0] = (__bf16)acc1[2*t]; p1.h[1] = (__bf16)acc1[2*t+1];
    obu[(rowbase + 8 + t)*64 + lane] = p1.u;
  }
  if (hi == 0)
    lsumb[((size_t)win*32 + ph)*32 + lo] = lsum;
}

// ---------------- final blend: gather <=4 window contributions ----------------
// out = x + gamma * (sum_win ew_i*ew_j*O_win/lsum_win) / (cnt + 1e-8).
// Fragment decode: query qc -> a=qc&3, hi=(qc>>2)&1, b2=qc>>3; r=a+4*b2;
// row t=r>>1, elem=r&1, lane=hi*32+(c&31). A w4-group (qc0 mult of 4) needs
// rows {2*b2, 2*b2+1} at one lane -> two 4B loads + one float4 lsum load.
__global__ __launch_bounds__(256) void final_kernel(
    const float* __restrict__ x, const float* __restrict__ gamma,
    const unsigned* __restrict__ obu, const float* __restrict__ lsumb,
    float* __restrict__ out)
{
  int idx4 = blockIdx.x * 256 + threadIdx.x;   // < B*C*H*W/4
  int w4    = idx4 % (Wn/4);
  int rowid = idx4 / (Wn/4);
  int h  = rowid % Hn;
  int cb = rowid / Hn;          // b*64 + c
  int c  = cb & 63;
  int b  = cb >> 6;
  int w0 = w4*4;

  int ihi = h  / STRIDEn; if (ihi > NHn-1) ihi = NHn-1;
  int jhi = w0 / STRIDEn; if (jhi > NWn-1) jhi = NWn-1;

  float s0 = 0.f, s1 = 0.f, s2 = 0.f, s3 = 0.f;
  #pragma unroll
  for (int dy = 0; dy < 2; ++dy) {
    int wi = ihi - dy;
    if (wi < 0) continue;
    int ph = h - STRIDEn*wi;
    if (ph >= WSn) continue;
    float ewi = edge_w(wi, ph);
    #pragma unroll
    for (int dx = 0; dx < 2; ++dx) {
      int wj = jhi - dx;
      if (wj < 0) continue;
      int pw0 = w0 - STRIDEn*wj;
      if (pw0 >= WSn) continue;
      int win = b*81 + wi*9 + wj;
      size_t rowbase = ((size_t)win*32 + ph)*16 + (size_t)(c>>5)*8;
      int k = pw0 >> 2;
      int lane2 = ((k & 1) << 5) | (c & 31);
      int b2 = k >> 1;
      unsigned u0 = obu[(rowbase + 2*b2    )*64 + lane2];   // qc0+0, qc0+1
      unsigned u1 = obu[(rowbase + 2*b2 + 1)*64 + lane2];   // qc0+2, qc0+3
      float4 ls4 = *(const float4*)(lsumb + ((size_t)win*32 + ph)*32 + pw0);
      float e0 = ewi * edge_w(wj, pw0+0) * fast_rcp(ls4.x);
      float e1 = ewi * edge_w(wj, pw0+1) * fast_rcp(ls4.y);
      float e2 = ewi * edge_w(wj, pw0+2) * fast_rcp(ls4.z);
      float e3 = ewi * edge_w(wj, pw0+3) * fast_rcp(ls4.w);
      s0 = fmaf(bflo(u0), e0, s0);
      s1 = fmaf(bfhi(u0), e1, s1);
      s2 = fmaf(bflo(u1), e2, s2);
      s3 = fmaf(bfhi(u1), e3, s3);
    }
  }

  float g = gamma[0];
  float rs = covsum(h);
  float i0 = fast_rcp(rs * covsum(w0+0) + 1e-8f);
  float i1 = fast_rcp(rs * covsum(w0+1) + 1e-8f);
  float i2 = fast_rcp(rs * covsum(w0+2) + 1e-8f);
  float i3 = fast_rcp(rs * covsum(w0+3) + 1e-8f);
  float4 xv = ((const float4*)x)[idx4];
  float4 r;
  r.x = xv.x + g * s0 * i0;
  r.y = xv.y + g * s1 * i1;
  r.z = xv.z + g * s2 * i2;
  r.w = xv.w + g * s3 * i3;
  ((float4*)out)[idx4] = r;
}

extern "C" void kernel_launch(void* const* d_in, const int* in_sizes, int n_in,
                              void* d_out, int out_size, void* d_ws, size_t ws_size,
                              hipStream_t stream) {
  const float* x     = (const float*)d_in[0];
  const float* Wq    = (const float*)d_in[1];
  const float* bq    = (const float*)d_in[2];
  const float* Wk    = (const float*)d_in[3];
  const float* bk    = (const float*)d_in[4];
  const float* Wv    = (const float*)d_in[5];
  const float* bv    = (const float*)d_in[6];
  const float* gamma = (const float*)d_in[7];
  float* out = (float*)d_out;

  __bf16*   qb    = (__bf16*)d_ws;                         // B*H*W*8          (1.6 MB)
  __bf16*   kb    = qb  + (size_t)Bn*HWn*8;                // B*H*W*8          (1.6 MB)
  __bf16*   vb2   = kb  + (size_t)Bn*HWn*8;                // B*C*H*W w8-tiled (12.8 MB)
  unsigned* obu   = (unsigned*)(vb2 + (size_t)Bn*Cn*HWn);  // 162*32*16*64 u32 (21.2 MB)
  float*    lsumb = (float*)(obu + (size_t)162*32*16*64);  // 162*32*32 f32    (0.66 MB)

  qkv_kernel<<<(Bn*HWn/256)*3, 256, 0, stream>>>(x, Wq, bq, Wk, bk, Wv, bv, qb, kb, vb2);
  attn_kernel<<<Bn*NHn*NWn*8, 256, 0, stream>>>(qb, kb, vb2, obu, lsumb);
  final_kernel<<<(Bn*Cn*HWn/4)/256, 256, 0, stream>>>(x, gamma, obu, lsumb, out);
}

// Round 10
// 105.337 us; speedup vs baseline: 1.4883x; 1.4883x over previous
//
#include <hip/hip_runtime.h>

#define Bn 2
#define Cn 64
#define Hn 224
#define Wn 224
#define HWn (Hn*Wn)
#define WSn 32
#define OVn 8
#define STRIDEn 24
#define NHn 9
#define NWn 9
#define NWT 28                 // W/8 tiles per row
#define VROW (NWT*Cn*8)        // 14336 elements per (b,h) row in vb2
#define QSCALE (1.44269504088896f/32.0f)

typedef __bf16 bf16x8 __attribute__((ext_vector_type(8)));
typedef __bf16 bf16x4 __attribute__((ext_vector_type(4)));
typedef float f32x16 __attribute__((ext_vector_type(16)));
typedef unsigned int uint4v __attribute__((ext_vector_type(4)));

union PackU { uint4v u; bf16x8 h; };
union BfPair { __bf16 h[2]; unsigned u; };

__device__ __forceinline__ float fast_exp2(float x) {
#if __has_builtin(__builtin_amdgcn_exp2f)
  return __builtin_amdgcn_exp2f(x);
#else
  return exp2f(x);
#endif
}

__device__ __forceinline__ float fast_rcp(float x) {
#if __has_builtin(__builtin_amdgcn_rcpf)
  return __builtin_amdgcn_rcpf(x);
#else
  return 1.0f / x;
#endif
}

// fade weight factor for window index i, in-window position p
__device__ __forceinline__ float edge_w(int i, int p) {
  float w = 1.0f;
  if (i > 0 && p < OVn)            w *= (float)p * (1.0f/7.0f);
  if (i < NHn-1 && p >= WSn-OVn)   w *= (float)(WSn-1-p) * (1.0f/7.0f);
  return w;
}

// separable coverage sum
__device__ __forceinline__ float covsum(int h) {
  int ihi = h / STRIDEn; if (ihi > NHn-1) ihi = NHn-1;
  float s = edge_w(ihi, h - STRIDEn*ihi);
  int ilo = ihi - 1;
  if (ilo >= 0) {
    int p = h - STRIDEn*ilo;
    if (p < WSn) s += edge_w(ilo, p);
  }
  return s;
}

// ---------------- QKV projection: fp32 in, bf16 out ----------------
// 3-role split (4704 waves): role 0: q8+k8; roles 1,2: v halves.
// qb: [pix][8] bf16 PRE-SCALED by log2e/32.  kb: [pix][8] bf16.
// vb2: [b][h][w/8][c][w%8] bf16 (w8-tiled, coalesced PV fragment loads).
__global__ __launch_bounds__(256) void qkv_kernel(
    const float* __restrict__ x,
    const float* __restrict__ Wq, const float* __restrict__ bq,
    const float* __restrict__ Wk, const float* __restrict__ bk,
    const float* __restrict__ Wv, const float* __restrict__ bv,
    __bf16* __restrict__ qb, __bf16* __restrict__ kb, __bf16* __restrict__ vb2)
{
  __shared__ float sW[32*64];
  __shared__ float sb2[32];
  int bid = blockIdx.x;
  int pb = bid / 3, role = bid - pb*3;
  int tid = threadIdx.x;

  if (role == 0) {
    for (int i = tid; i < 8*64; i += 256) { sW[i] = Wq[i]; sW[512 + i] = Wk[i]; }
    if (tid < 8) { sb2[tid] = bq[tid]; sb2[8 + tid] = bk[tid]; }
  } else {
    const float* Wsrc = Wv + (size_t)(role-1)*32*64;
    for (int i = tid; i < 32*64; i += 256) sW[i] = Wsrc[i];
    if (tid < 32) sb2[tid] = bv[(role-1)*32 + tid];
  }
  __syncthreads();

  int pix = pb*256 + tid;                // B*H*W = 100352 = 392*256
  int b  = pix / HWn;
  int hw = pix - b * HWn;
  const float* xp = x + (size_t)b * Cn * HWn + hw;
  float xr[64];
  #pragma unroll
  for (int c = 0; c < 64; ++c) xr[c] = xp[(size_t)c * HWn];

  if (role == 0) {
    float q8[8], k8[8];
    #pragma unroll
    for (int o = 0; o < 8; ++o) {
      const float4* wrq = (const float4*)(sW + o*64);
      const float4* wrk = (const float4*)(sW + 512 + o*64);
      float sq = sb2[o], sk = sb2[8+o];
      #pragma unroll
      for (int c4 = 0; c4 < 16; ++c4) {
        float4 wq4 = wrq[c4]; float4 wk4 = wrk[c4];
        sq = fmaf(wq4.x, xr[4*c4+0], sq); sq = fmaf(wq4.y, xr[4*c4+1], sq);
        sq = fmaf(wq4.z, xr[4*c4+2], sq); sq = fmaf(wq4.w, xr[4*c4+3], sq);
        sk = fmaf(wk4.x, xr[4*c4+0], sk); sk = fmaf(wk4.y, xr[4*c4+1], sk);
        sk = fmaf(wk4.z, xr[4*c4+2], sk); sk = fmaf(wk4.w, xr[4*c4+3], sk);
      }
      q8[o] = sq; k8[o] = sk;
    }
    PackU qo, ko;
    #pragma unroll
    for (int o = 0; o < 8; ++o) {
      qo.h[o] = (__bf16)(q8[o] * QSCALE);
      ko.h[o] = (__bf16)k8[o];
    }
    *(uint4v*)(qb + (size_t)pix*8) = qo.u;
    *(uint4v*)(kb + (size_t)pix*8) = ko.u;
  } else {
    int h = hw / Wn, w = hw - h*Wn;
    __bf16* vo = vb2 + (((size_t)(b*Hn + h)*NWT + (w >> 3))*Cn + (size_t)(role-1)*32)*8 + (w & 7);
    for (int og = 0; og < 8; ++og) {
      #pragma unroll
      for (int t = 0; t < 4; ++t) {
        int o = og*4 + t;
        const float4* wr = (const float4*)(sW + o*64);
        float s = sb2[o];
        #pragma unroll
        for (int c4 = 0; c4 < 16; ++c4) {
          float4 w4 = wr[c4];
          s = fmaf(w4.x, xr[4*c4+0], s); s = fmaf(w4.y, xr[4*c4+1], s);
          s = fmaf(w4.z, xr[4*c4+2], s); s = fmaf(w4.w, xr[4*c4+3], s);
        }
        vo[(size_t)o * 8] = (__bf16)s;
      }
    }
  }
}

// ---------------- MFMA flash attention ----------------
// One wave = (window, query-row ph): all 1024 keys, fully independent.
// Block = 256 threads = 4 waves (4 ph rows); grid = 162*8 = 1296 blocks.
// No merge, no lsum side-buffer. Epilogue: per-wave LDS transpose with
// edge_w/lsum applied -> ob2 [win][c][p] bf16 (coalesced gather in final).
__global__ __launch_bounds__(256, 4) void attn_kernel(
    const __bf16* __restrict__ qb, const __bf16* __restrict__ kb,
    const __bf16* __restrict__ vb2, __bf16* __restrict__ ob2)
{
  __shared__ float LB[4*2112];    // per-wave [2][32][33] transpose tiles (33.8 KB)

  // XCD swizzle: 1296 = 8*162; all 8 blocks of a window land on one XCD.
  int bid = blockIdx.x;
  int bidm = (bid & 7) * 162 + (bid >> 3);
  int win = bidm >> 3;            // 0..161
  int rg  = bidm & 7;             // row-group 0..7
  int b  = win / (NHn*NWn);
  int ij = win - b*(NHn*NWn);
  int wi = ij / NWn;
  int wj = ij - wi*NWn;

  int tid  = threadIdx.x;
  int widx = tid >> 6;            // wave 0..3
  int lane = tid & 63;
  int ph = rg*4 + widx;           // query row 0..31
  int lo = lane & 31, hi = lane >> 5;
  int h0 = wi*STRIDEn, w0 = wj*STRIDEn;

  // Q fragment (B operand): lane holds Q[query=lo][ch=8*hi+j]; hi lanes zeroed (ch 8..15 pad)
  bf16x8 qf = *(const bf16x8*)(qb + ((size_t)(b*Hn + h0 + ph)*Wn + w0 + lo) * 8);
  if (hi) qf = (bf16x8){};

  // K rows; hi lanes duplicate lo (annihilated by qf==0 rows)
  const __bf16* kbase = kb + ((size_t)(b*Hn + h0)*Wn + w0 + lo) * 8;
  // V in w8-tiled layout; lane (lo,hi) -> (ch=lo, wtile=w0/8 + hi)
  const __bf16* vbase = vb2 + (((size_t)(b*Hn + h0)*NWT + (w0>>3))*Cn + lo)*8
                        + (size_t)hi*512;

  f32x16 acc0 = {}, acc1 = {};
  float ls[4] = {0.f, 0.f, 0.f, 0.f};   // partial sums break the serial add chain

  #pragma unroll 4
  for (int kt = 0; kt < 32; ++kt) {
    bf16x8 kf = *(const bf16x8*)(kbase + (size_t)kt*Wn*8);

    const __bf16* vk = vbase + (size_t)kt*VROW;
    bf16x8 vf00 = *(const bf16x8*)(vk);           // keys 8*hi+j,    ch lo
    bf16x8 vf01 = *(const bf16x8*)(vk + 256);     // keys 8*hi+j,    ch lo+32
    bf16x8 vf10 = *(const bf16x8*)(vk + 1024);    // keys 16+8*hi+j, ch lo
    bf16x8 vf11 = *(const bf16x8*)(vk + 1280);    // keys 16+8*hi+j, ch lo+32

    // S[key][query]: key=(r&3)+8*(r>>2)+4*hi (w-offset), query=lo. log2 domain.
    f32x16 s = __builtin_amdgcn_mfma_f32_32x32x16_bf16(kf, qf, (f32x16){}, 0, 0, 0);

    unsigned w[8];
    #pragma unroll
    for (int d = 0; d < 8; ++d) {
      float a  = fast_exp2(s[2*d]);
      float b2 = fast_exp2(s[2*d+1]);
      ls[d & 3] += a + b2;
      BfPair pr; pr.h[0] = (__bf16)a; pr.h[1] = (__bf16)b2;
      w[d] = pr.u;
    }
    // permlane32_swap: one op yields BOTH PV-fragment words.
    auto s02 = __builtin_amdgcn_permlane32_swap((int)w[0], (int)w[2], false, false);
    auto s13 = __builtin_amdgcn_permlane32_swap((int)w[1], (int)w[3], false, false);
    auto s46 = __builtin_amdgcn_permlane32_swap((int)w[4], (int)w[6], false, false);
    auto s57 = __builtin_amdgcn_permlane32_swap((int)w[5], (int)w[7], false, false);

    PackU pa0, pa1;
    pa0.u = (uint4v){(unsigned)s02[0], (unsigned)s13[0], (unsigned)s02[1], (unsigned)s13[1]};
    pa1.u = (uint4v){(unsigned)s46[0], (unsigned)s57[0], (unsigned)s46[1], (unsigned)s57[1]};

    __builtin_amdgcn_s_setprio(1);
    acc0 = __builtin_amdgcn_mfma_f32_32x32x16_bf16(pa0.h, vf00, acc0, 0, 0, 0);
    acc1 = __builtin_amdgcn_mfma_f32_32x32x16_bf16(pa0.h, vf01, acc1, 0, 0, 0);
    acc0 = __builtin_amdgcn_mfma_f32_32x32x16_bf16(pa1.h, vf10, acc0, 0, 0, 0);
    acc1 = __builtin_amdgcn_mfma_f32_32x32x16_bf16(pa1.h, vf11, acc1, 0, 0, 0);
    __builtin_amdgcn_s_setprio(0);
  }

  float lsum = (ls[0] + ls[1]) + (ls[2] + ls[3]);
  // partner half-wave holds the complementary key set for the same query lo
  lsum += __shfl_xor(lsum, 32);
  float sc = edge_w(wi, ph) * edge_w(wj, lo) * fast_rcp(lsum);  // lane's query col = lo

  // per-wave transpose: acc layout D[qc=(r&3)+8*(r>>2)+4*hi][ch=lo] -> [c][p] stores
  float* T = LB + (size_t)widx*2112;    // [2][32][33]
  #pragma unroll
  for (int r = 0; r < 16; ++r) {
    int qc = (r&3) + 8*(r>>2) + 4*hi;
    T[qc*33 + lo]        = acc0[r];
    T[1056 + qc*33 + lo] = acc1[r];
  }
  __syncthreads();
  // ob2 layout: [win(162)][c(64)][p(1024)], p = ph*32 + qc
  __bf16* ob = ob2 + ((size_t)win*64)*1024 + ph*32;
  #pragma unroll
  for (int rr = 0; rr < 16; ++rr) {
    int c0 = 2*rr + hi;
    ob[(size_t)c0*1024 + lo]        = (__bf16)(T[lo*33 + c0] * sc);
    ob[(size_t)(32 + c0)*1024 + lo] = (__bf16)(T[1056 + lo*33 + c0] * sc);
  }
}

// ---------------- final blend: gather <=4 window contributions ----------------
// out = x + gamma * (sum of stored wgt*ow/lsum) / (cnt + 1e-8), cnt separable.
// Window-coverage boundaries (24*j and 24*j+32) are multiples of 4, so an
// aligned w4-group has a constant covering-window set -> bf16x4 loads.
__global__ __launch_bounds__(256) void final_kernel(
    const float* __restrict__ x, const float* __restrict__ gamma,
    const __bf16* __restrict__ ob2, float* __restrict__ out)
{
  int idx4 = blockIdx.x * 256 + threadIdx.x;   // < B*C*H*W/4
  int w4    = idx4 % (Wn/4);
  int rowid = idx4 / (Wn/4);
  int h  = rowid % Hn;
  int cb = rowid / Hn;          // b*64 + c
  int c  = cb & 63;
  int b  = cb >> 6;
  int w0 = w4*4;

  int ihi = h  / STRIDEn; if (ihi > NHn-1) ihi = NHn-1;
  int jhi = w0 / STRIDEn; if (jhi > NWn-1) jhi = NWn-1;

  float s0 = 0.f, s1 = 0.f, s2 = 0.f, s3 = 0.f;
  #pragma unroll
  for (int dy = 0; dy < 2; ++dy) {
    int wi = ihi - dy;
    if (wi < 0) continue;
    int ph = h - STRIDEn*wi;
    if (ph >= WSn) continue;
    #pragma unroll
    for (int dx = 0; dx < 2; ++dx) {
      int wj = jhi - dx;
      if (wj < 0) continue;
      int pw = w0 - STRIDEn*wj;
      if (pw >= WSn) continue;
      const __bf16* src = ob2 + (((size_t)(b*81 + wi*9 + wj)*64 + c) << 10) + ph*WSn + pw;
      bf16x4 v = *(const bf16x4*)src;
      s0 += (float)v[0]; s1 += (float)v[1]; s2 += (float)v[2]; s3 += (float)v[3];
    }
  }

  float g = gamma[0];
  float rs = covsum(h);
  float i0 = fast_rcp(rs * covsum(w0+0) + 1e-8f);
  float i1 = fast_rcp(rs * covsum(w0+1) + 1e-8f);
  float i2 = fast_rcp(rs * covsum(w0+2) + 1e-8f);
  float i3 = fast_rcp(rs * covsum(w0+3) + 1e-8f);
  float4 xv = ((const float4*)x)[idx4];
  float4 r;
  r.x = xv.x + g * s0 * i0;
  r.y = xv.y + g * s1 * i1;
  r.z = xv.z + g * s2 * i2;
  r.w = xv.w + g * s3 * i3;
  ((float4*)out)[idx4] = r;
}

extern "C" void kernel_launch(void* const* d_in, const int* in_sizes, int n_in,
                              void* d_out, int out_size, void* d_ws, size_t ws_size,
                              hipStream_t stream) {
  const float* x     = (const float*)d_in[0];
  const float* Wq    = (const float*)d_in[1];
  const float* bq    = (const float*)d_in[2];
  const float* Wk    = (const float*)d_in[3];
  const float* bk    = (const float*)d_in[4];
  const float* Wv    = (const float*)d_in[5];
  const float* bv    = (const float*)d_in[6];
  const float* gamma = (const float*)d_in[7];
  float* out = (float*)d_out;

  __bf16* qb  = (__bf16*)d_ws;                       // B*H*W*8          (1.6 MB)
  __bf16* kb  = qb  + (size_t)Bn*HWn*8;              // B*H*W*8          (1.6 MB)
  __bf16* vb2 = kb  + (size_t)Bn*HWn*8;              // B*C*H*W w8-tiled (12.8 MB)
  __bf16* ob2 = vb2 + (size_t)Bn*Cn*HWn;             // 162*64*1024      (21.2 MB)

  qkv_kernel<<<(Bn*HWn/256)*3, 256, 0, stream>>>(x, Wq, bq, Wk, bk, Wv, bv, qb, kb, vb2);
  attn_kernel<<<Bn*NHn*NWn*8, 256, 0, stream>>>(qb, kb, vb2, ob2);
  final_kernel<<<(Bn*Cn*HWn/4)/256, 256, 0, stream>>>(x, gamma, ob2, out);
}

// Round 11
// 79.642 us; speedup vs baseline: 1.9684x; 1.3226x over previous
//
#include <hip/hip_runtime.h>

#define Bn 2
#define Cn 64
#define Hn 224
#define Wn 224
#define HWn (Hn*Wn)
#define WSn 32
#define OVn 8
#define STRIDEn 24
#define NHn 9
#define NWn 9
#define NWT 28                 // W/8 tiles per row
#define VROW (NWT*Cn*8)        // 14336 elements per (b,h) row in vb2
#define QSCALE (1.44269504088896f/32.0f)

typedef __bf16 bf16x8 __attribute__((ext_vector_type(8)));
typedef __bf16 bf16x4 __attribute__((ext_vector_type(4)));
typedef float f32x16 __attribute__((ext_vector_type(16)));
typedef unsigned int uint4v __attribute__((ext_vector_type(4)));

union PackU { uint4v u; bf16x8 h; };
union BfPair { __bf16 h[2]; unsigned u; };

__device__ __forceinline__ float fast_exp2(float x) {
#if __has_builtin(__builtin_amdgcn_exp2f)
  return __builtin_amdgcn_exp2f(x);
#else
  return exp2f(x);
#endif
}

__device__ __forceinline__ float fast_rcp(float x) {
#if __has_builtin(__builtin_amdgcn_rcpf)
  return __builtin_amdgcn_rcpf(x);
#else
  return 1.0f / x;
#endif
}

// fade weight factor for window index i, in-window position p
__device__ __forceinline__ float edge_w(int i, int p) {
  float w = 1.0f;
  if (i > 0 && p < OVn)            w *= (float)p * (1.0f/7.0f);
  if (i < NHn-1 && p >= WSn-OVn)   w *= (float)(WSn-1-p) * (1.0f/7.0f);
  return w;
}

// separable coverage sum
__device__ __forceinline__ float covsum(int h) {
  int ihi = h / STRIDEn; if (ihi > NHn-1) ihi = NHn-1;
  float s = edge_w(ihi, h - STRIDEn*ihi);
  int ilo = ihi - 1;
  if (ilo >= 0) {
    int p = h - STRIDEn*ilo;
    if (p < WSn) s += edge_w(ilo, p);
  }
  return s;
}

// ---------------- QKV projection via MFMA ----------------
// C[80 x 100352] = Wall[80 x 64] * X[64 x 100352], one wave = 32 pixels
// (one aligned w-group; W=224=7*32). A = Wall rows: 0-7 Wq (pre-scaled by
// QSCALE), 8-15 Wk, 16-79 Wv, 80-95 zero pad. x read ONCE (fp32->bf16).
// qb: [pix][8] bf16 (q pre-scaled). kb: [pix][8]. vb2: [b][h][w/8][c][w%8].
__global__ __launch_bounds__(256) void qkv_kernel(
    const float* __restrict__ x,
    const float* __restrict__ Wq, const float* __restrict__ bq,
    const float* __restrict__ Wk, const float* __restrict__ bk,
    const float* __restrict__ Wv, const float* __restrict__ bv,
    __bf16* __restrict__ qb, __bf16* __restrict__ kb, __bf16* __restrict__ vb2)
{
  __shared__ __attribute__((aligned(16))) __bf16 sA[3][4][64][8];  // 12 KB A-frags
  __shared__ float sBias[96];
  __shared__ float sT[4][32*17];                                   // per-wave q/k transpose

  int tid = threadIdx.x;
  // stage A fragments: frag f -> (tile t, kstep s, lane): lane holds A[row=t*32+(l&31)][ch=s*16+8*(l>>5)+j]
  for (int f = tid; f < 768; f += 256) {
    int t = f >> 8;
    int rem = f & 255;
    int s = rem >> 6;
    int ln = rem & 63;
    int row = t*32 + (ln & 31);
    int ch  = s*16 + (ln >> 5)*8;
    const float* src = nullptr;
    float scale = 1.0f;
    if (row < 8)       { src = Wq + row*64 + ch; scale = QSCALE; }
    else if (row < 16) { src = Wk + (row-8)*64 + ch; }
    else if (row < 80) { src = Wv + (row-16)*64 + ch; }
    bf16x8 a = {};
    if (src) {
      #pragma unroll
      for (int j = 0; j < 8; ++j) a[j] = (__bf16)(src[j] * scale);
    }
    *(bf16x8*)&sA[t][s][ln][0] = a;
  }
  if (tid < 96) {
    float bb = 0.f;
    if (tid < 8)       bb = bq[tid] * QSCALE;
    else if (tid < 16) bb = bk[tid-8];
    else if (tid < 80) bb = bv[tid-16];
    sBias[tid] = bb;
  }
  __syncthreads();

  int widx = tid >> 6;
  int lane = tid & 63;
  int lo = lane & 31, hi = lane >> 5;
  int gid = blockIdx.x*4 + widx;        // 3136 wave-groups = 2*224*7
  int wg  = gid % 7;
  int rem = gid / 7;
  int h = rem % Hn;
  int b = rem / Hn;
  int w0 = wg * 32;
  const float* xb = x + (size_t)b*Cn*HWn + (size_t)h*Wn + w0 + lo;

  f32x16 d0 = {}, d1 = {}, d2 = {};
  #pragma unroll
  for (int s = 0; s < 4; ++s) {
    // B frag: lane holds X[ch=s*16+8*hi+j][pix=lo]; coalesced 128B per j
    bf16x8 bfr;
    #pragma unroll
    for (int j = 0; j < 8; ++j)
      bfr[j] = (__bf16)xb[(size_t)(s*16 + 8*hi + j)*HWn];
    bf16x8 a0 = *(const bf16x8*)&sA[0][s][lane][0];
    bf16x8 a1 = *(const bf16x8*)&sA[1][s][lane][0];
    bf16x8 a2 = *(const bf16x8*)&sA[2][s][lane][0];
    d0 = __builtin_amdgcn_mfma_f32_32x32x16_bf16(a0, bfr, d0, 0, 0, 0);
    d1 = __builtin_amdgcn_mfma_f32_32x32x16_bf16(a1, bfr, d1, 0, 0, 0);
    d2 = __builtin_amdgcn_mfma_f32_32x32x16_bf16(a2, bfr, d2, 0, 0, 0);
  }

  // ---- q/k epilogue: tile0 regs 0..7 are rows 0..15; transpose to pixel-major ----
  float* T = sT[widx];
  #pragma unroll
  for (int r = 0; r < 8; ++r) {
    int row = (r&3) + 8*(r>>2) + 4*hi;          // 0..15
    T[lo*17 + row] = d0[r] + sBias[row];
  }
  __syncthreads();
  PackU o;
  #pragma unroll
  for (int m = 0; m < 8; ++m) o.h[m] = (__bf16)T[lo*17 + hi*8 + m];
  size_t pix = (size_t)(b*Hn + h)*Wn + w0 + lo;
  if (hi == 0) *(uint4v*)(qb + pix*8) = o.u;
  else         *(uint4v*)(kb + pix*8) = o.u;

  // ---- v stores: rows 16..79 -> c = row-16, w8-tiled layout ----
  __bf16* vbl = vb2 + ((size_t)(b*Hn + h)*NWT + (w0>>3))*(Cn*8)
                + (size_t)(lo>>3)*(Cn*8) + (lo&7);
  #pragma unroll
  for (int r = 8; r < 16; ++r) {
    int row = (r&3) + 8*(r>>2) + 4*hi;          // 16..31
    vbl[(size_t)(row-16)*8] = (__bf16)(d0[r] + sBias[row]);
  }
  #pragma unroll
  for (int r = 0; r < 16; ++r) {
    int row = 32 + (r&3) + 8*(r>>2) + 4*hi;     // 32..63
    vbl[(size_t)(row-16)*8] = (__bf16)(d1[r] + sBias[row]);
  }
  #pragma unroll
  for (int r = 0; r < 8; ++r) {
    int row = 64 + (r&3) + 8*(r>>2) + 4*hi;     // 64..79 (80..95 = pad, skipped)
    vbl[(size_t)(row-16)*8] = (__bf16)(d2[r] + sBias[row]);
  }
}

// ---------------- MFMA flash attention ----------------
// One wave = (window, query-row ph): all 1024 keys, fully independent.
// Block = 256 threads = 4 waves (4 ph rows); grid = 162*8 = 1296 blocks.
// No merge, no lsum side-buffer. Epilogue: per-wave LDS transpose with
// edge_w/lsum applied -> ob2 [win][c][p] bf16 (coalesced gather in final).
__global__ __launch_bounds__(256, 4) void attn_kernel(
    const __bf16* __restrict__ qb, const __bf16* __restrict__ kb,
    const __bf16* __restrict__ vb2, __bf16* __restrict__ ob2)
{
  __shared__ float LB[4*2112];    // per-wave [2][32][33] transpose tiles (33.8 KB)

  // XCD swizzle: 1296 = 8*162; all 8 blocks of a window land on one XCD.
  int bid = blockIdx.x;
  int bidm = (bid & 7) * 162 + (bid >> 3);
  int win = bidm >> 3;            // 0..161
  int rg  = bidm & 7;             // row-group 0..7
  int b  = win / (NHn*NWn);
  int ij = win - b*(NHn*NWn);
  int wi = ij / NWn;
  int wj = ij - wi*NWn;

  int tid  = threadIdx.x;
  int widx = tid >> 6;            // wave 0..3
  int lane = tid & 63;
  int ph = rg*4 + widx;           // query row 0..31
  int lo = lane & 31, hi = lane >> 5;
  int h0 = wi*STRIDEn, w0 = wj*STRIDEn;

  // Q fragment (B operand): lane holds Q[query=lo][ch=8*hi+j]; hi lanes zeroed (ch 8..15 pad)
  bf16x8 qf = *(const bf16x8*)(qb + ((size_t)(b*Hn + h0 + ph)*Wn + w0 + lo) * 8);
  if (hi) qf = (bf16x8){};

  // K rows; hi lanes duplicate lo (annihilated by qf==0 rows)
  const __bf16* kbase = kb + ((size_t)(b*Hn + h0)*Wn + w0 + lo) * 8;
  // V in w8-tiled layout; lane (lo,hi) -> (ch=lo, wtile=w0/8 + hi)
  const __bf16* vbase = vb2 + (((size_t)(b*Hn + h0)*NWT + (w0>>3))*Cn + lo)*8
                        + (size_t)hi*512;

  f32x16 acc0 = {}, acc1 = {};
  float ls[4] = {0.f, 0.f, 0.f, 0.f};   // partial sums break the serial add chain

  #pragma unroll 4
  for (int kt = 0; kt < 32; ++kt) {
    bf16x8 kf = *(const bf16x8*)(kbase + (size_t)kt*Wn*8);

    const __bf16* vk = vbase + (size_t)kt*VROW;
    bf16x8 vf00 = *(const bf16x8*)(vk);           // keys 8*hi+j,    ch lo
    bf16x8 vf01 = *(const bf16x8*)(vk + 256);     // keys 8*hi+j,    ch lo+32
    bf16x8 vf10 = *(const bf16x8*)(vk + 1024);    // keys 16+8*hi+j, ch lo
    bf16x8 vf11 = *(const bf16x8*)(vk + 1280);    // keys 16+8*hi+j, ch lo+32

    // S[key][query]: key=(r&3)+8*(r>>2)+4*hi (w-offset), query=lo. log2 domain.
    f32x16 s = __builtin_amdgcn_mfma_f32_32x32x16_bf16(kf, qf, (f32x16){}, 0, 0, 0);

    unsigned w[8];
    #pragma unroll
    for (int d = 0; d < 8; ++d) {
      float a  = fast_exp2(s[2*d]);
      float b2 = fast_exp2(s[2*d+1]);
      ls[d & 3] += a + b2;
      BfPair pr; pr.h[0] = (__bf16)a; pr.h[1] = (__bf16)b2;
      w[d] = pr.u;
    }
    // permlane32_swap: one op yields BOTH PV-fragment words.
    auto s02 = __builtin_amdgcn_permlane32_swap((int)w[0], (int)w[2], false, false);
    auto s13 = __builtin_amdgcn_permlane32_swap((int)w[1], (int)w[3], false, false);
    auto s46 = __builtin_amdgcn_permlane32_swap((int)w[4], (int)w[6], false, false);
    auto s57 = __builtin_amdgcn_permlane32_swap((int)w[5], (int)w[7], false, false);

    PackU pa0, pa1;
    pa0.u = (uint4v){(unsigned)s02[0], (unsigned)s13[0], (unsigned)s02[1], (unsigned)s13[1]};
    pa1.u = (uint4v){(unsigned)s46[0], (unsigned)s57[0], (unsigned)s46[1], (unsigned)s57[1]};

    __builtin_amdgcn_s_setprio(1);
    acc0 = __builtin_amdgcn_mfma_f32_32x32x16_bf16(pa0.h, vf00, acc0, 0, 0, 0);
    acc1 = __builtin_amdgcn_mfma_f32_32x32x16_bf16(pa0.h, vf01, acc1, 0, 0, 0);
    acc0 = __builtin_amdgcn_mfma_f32_32x32x16_bf16(pa1.h, vf10, acc0, 0, 0, 0);
    acc1 = __builtin_amdgcn_mfma_f32_32x32x16_bf16(pa1.h, vf11, acc1, 0, 0, 0);
    __builtin_amdgcn_s_setprio(0);
  }

  float lsum = (ls[0] + ls[1]) + (ls[2] + ls[3]);
  // partner half-wave holds the complementary key set for the same query lo
  lsum += __shfl_xor(lsum, 32);
  float sc = edge_w(wi, ph) * edge_w(wj, lo) * fast_rcp(lsum);  // lane's query col = lo

  // per-wave transpose: acc layout D[qc=(r&3)+8*(r>>2)+4*hi][ch=lo] -> [c][p] stores
  float* T = LB + (size_t)widx*2112;    // [2][32][33]
  #pragma unroll
  for (int r = 0; r < 16; ++r) {
    int qc = (r&3) + 8*(r>>2) + 4*hi;
    T[qc*33 + lo]        = acc0[r];
    T[1056 + qc*33 + lo] = acc1[r];
  }
  __syncthreads();
  // ob2 layout: [win(162)][c(64)][p(1024)], p = ph*32 + qc
  __bf16* ob = ob2 + ((size_t)win*64)*1024 + ph*32;
  #pragma unroll
  for (int rr = 0; rr < 16; ++rr) {
    int c0 = 2*rr + hi;
    ob[(size_t)c0*1024 + lo]        = (__bf16)(T[lo*33 + c0] * sc);
    ob[(size_t)(32 + c0)*1024 + lo] = (__bf16)(T[1056 + lo*33 + c0] * sc);
  }
}

// ---------------- final blend: gather <=4 window contributions ----------------
// out = x + gamma * (sum of stored wgt*ow/lsum) / (cnt + 1e-8), cnt separable.
// Window-coverage boundaries (24*j and 24*j+32) are multiples of 4, so an
// aligned w4-group has a constant covering-window set -> bf16x4 loads.
__global__ __launch_bounds__(256) void final_kernel(
    const float* __restrict__ x, const float* __restrict__ gamma,
    const __bf16* __restrict__ ob2, float* __restrict__ out)
{
  int idx4 = blockIdx.x * 256 + threadIdx.x;   // < B*C*H*W/4
  int w4    = idx4 % (Wn/4);
  int rowid = idx4 / (Wn/4);
  int h  = rowid % Hn;
  int cb = rowid / Hn;          // b*64 + c
  int c  = cb & 63;
  int b  = cb >> 6;
  int w0 = w4*4;

  int ihi = h  / STRIDEn; if (ihi > NHn-1) ihi = NHn-1;
  int jhi = w0 / STRIDEn; if (jhi > NWn-1) jhi = NWn-1;

  float s0 = 0.f, s1 = 0.f, s2 = 0.f, s3 = 0.f;
  #pragma unroll
  for (int dy = 0; dy < 2; ++dy) {
    int wi = ihi - dy;
    if (wi < 0) continue;
    int ph = h - STRIDEn*wi;
    if (ph >= WSn) continue;
    #pragma unroll
    for (int dx = 0; dx < 2; ++dx) {
      int wj = jhi - dx;
      if (wj < 0) continue;
      int pw = w0 - STRIDEn*wj;
      if (pw >= WSn) continue;
      const __bf16* src = ob2 + (((size_t)(b*81 + wi*9 + wj)*64 + c) << 10) + ph*WSn + pw;
      bf16x4 v = *(const bf16x4*)src;
      s0 += (float)v[0]; s1 += (float)v[1]; s2 += (float)v[2]; s3 += (float)v[3];
    }
  }

  float g = gamma[0];
  float rs = covsum(h);
  float i0 = fast_rcp(rs * covsum(w0+0) + 1e-8f);
  float i1 = fast_rcp(rs * covsum(w0+1) + 1e-8f);
  float i2 = fast_rcp(rs * covsum(w0+2) + 1e-8f);
  float i3 = fast_rcp(rs * covsum(w0+3) + 1e-8f);
  float4 xv = ((const float4*)x)[idx4];
  float4 r;
  r.x = xv.x + g * s0 * i0;
  r.y = xv.y + g * s1 * i1;
  r.z = xv.z + g * s2 * i2;
  r.w = xv.w + g * s3 * i3;
  ((float4*)out)[idx4] = r;
}

extern "C" void kernel_launch(void* const* d_in, const int* in_sizes, int n_in,
                              void* d_out, int out_size, void* d_ws, size_t ws_size,
                              hipStream_t stream) {
  const float* x     = (const float*)d_in[0];
  const float* Wq    = (const float*)d_in[1];
  const float* bq    = (const float*)d_in[2];
  const float* Wk    = (const float*)d_in[3];
  const float* bk    = (const float*)d_in[4];
  const float* Wv    = (const float*)d_in[5];
  const float* bv    = (const float*)d_in[6];
  const float* gamma = (const float*)d_in[7];
  float* out = (float*)d_out;

  __bf16* qb  = (__bf16*)d_ws;                       // B*H*W*8          (1.6 MB)
  __bf16* kb  = qb  + (size_t)Bn*HWn*8;              // B*H*W*8          (1.6 MB)
  __bf16* vb2 = kb  + (size_t)Bn*HWn*8;              // B*C*H*W w8-tiled (12.8 MB)
  __bf16* ob2 = vb2 + (size_t)Bn*Cn*HWn;             // 162*64*1024      (21.2 MB)

  qkv_kernel<<<784, 256, 0, stream>>>(x, Wq, bq, Wk, bk, Wv, bv, qb, kb, vb2);
  attn_kernel<<<Bn*NHn*NWn*8, 256, 0, stream>>>(qb, kb, vb2, ob2);
  final_kernel<<<(Bn*Cn*HWn/4)/256, 256, 0, stream>>>(x, gamma, ob2, out);
}